// Round 8
// baseline (321.143 us; speedup 1.0000x reference)
//
#include <hip/hip_runtime.h>

#define BLK 256
#define DD  48
#define STR 257   // odd stride: transposed LDS tile, <=2-way banking (free) on read
#define INV2PI 0.15915494309189535f   // v_sin/v_cos take revolutions

// rho = a0*I + v.sigma (a0, v complex). Conjugation by U_k = Rz(-p1k)Ry(p0k)Rz(-p2k)
// leaves a0 invariant and rotates v. Adjacent Rz's merge across blocks:
//   Z(-p2_0); k=0..14: Y(p0_k), Z(-(p1_k+p2_{k+1})); Y(p0_15); Z(-p1_15)
// => 33 rotations / 66 native trig. x is staged per half-row (24 floats/elem)
// through a transposed LDS tile so global reads are coalesced.
__global__ __launch_bounds__(BLK) void qlayer_kernel(
    const float* __restrict__ rho_real,
    const float* __restrict__ rho_imag,
    const float* __restrict__ x,
    const float* __restrict__ w,
    const float* __restrict__ theta,
    float* __restrict__ out,
    long long n,            // number of elements B
    long long out_floats)   // d_out capacity in floats (4*n: REAL part only)
{
    __shared__ float sx[24 * STR];   // 24.7 KB -> 6 blocks/CU

    const int tid = threadIdx.x;
    const long long blockBase = (long long)blockIdx.x * BLK;
    const long long b = blockBase + tid;
    const bool active = (b < n);

    // --- rho load + Bloch decomposition (overlaps with staging below) ---
    float a0r = 0.f, v1r = 0.f, v1i = 0.f, v2r = 0.f, v2i = 0.f, v3r = 0.f, v3i = 0.f;
    if (active) {
        float4 rr = reinterpret_cast<const float4*>(rho_real)[b];
        float4 ri = reinterpret_cast<const float4*>(rho_imag)[b];
        a0r = 0.5f * (rr.x + rr.w);
        v1r = 0.5f * (rr.y + rr.z);  v1i = 0.5f * (ri.y + ri.z);
        v2r = 0.5f * (ri.z - ri.y);  v2i = 0.5f * (rr.y - rr.z);
        v3r = 0.5f * (rr.x - rr.w);  v3i = 0.5f * (ri.x - ri.w);
    }

    const float4* __restrict__ x4 = reinterpret_cast<const float4*>(x);

    // stage half h (24 floats x 256 elements), near-coalesced global reads
    auto stage = [&](int h) {
        #pragma unroll
        for (int i = 0; i < 6; ++i) {
            int f = tid + BLK * i;          // 0..1535
            int e = f / 6;                  // element within block
            int q = f - 6 * e;              // float4 within half-row
            long long ge = blockBase + e;
            float4 v = make_float4(0.f, 0.f, 0.f, 0.f);
            if (ge < n) v = x4[ge * 12 + h * 6 + q];
            int jb = 4 * q;
            sx[(jb + 0) * STR + e] = v.x;
            sx[(jb + 1) * STR + e] = v.y;
            sx[(jb + 2) * STR + e] = v.z;
            sx[(jb + 3) * STR + e] = v.w;
        }
    };

    auto rotZ = [&](float ang) {   // == Rz(-ang) on (v1,v2)
        float s = __builtin_amdgcn_sinf(ang * INV2PI);
        float c = __builtin_amdgcn_cosf(ang * INV2PI);
        float t1r = fmaf(c, v1r,  s * v2r);
        float t1i = fmaf(c, v1i,  s * v2i);
        v2r = fmaf(c, v2r, -s * v1r);
        v2i = fmaf(c, v2i, -s * v1i);
        v1r = t1r; v1i = t1i;
    };
    auto rotY = [&](float ang) {   // == Ry(+ang) on (v1,v3)
        float s = __builtin_amdgcn_sinf(ang * INV2PI);
        float c = __builtin_amdgcn_cosf(ang * INV2PI);
        float t1r = fmaf(c, v1r,  s * v3r);
        float t1i = fmaf(c, v1i,  s * v3i);
        v3r = fmaf(c, v3r, -s * v1r);
        v3i = fmaf(c, v3i, -s * v1i);
        v1r = t1r; v1i = t1i;
    };
    // LDS fetch of x[j] for this thread's element; ROW must be compile-time (j%24)
    auto xl = [&](int row) { return sx[row * STR + tid]; };

    // ---- half A: j = 0..23 ----
    stage(0);
    __syncthreads();

    rotZ(fmaf(xl(2), w[2], theta[2]));                       // Z(-p2_0)
    #pragma unroll
    for (int k = 0; k < 7; ++k) {
        const int j = 3 * k;
        rotY(fmaf(xl(j), w[j], theta[j]));                   // Y(p0_k)
        float ts = theta[j + 1] + theta[j + 5];              // scalar math
        rotZ(fmaf(xl(j + 1), w[j + 1], fmaf(xl(j + 5), w[j + 5], ts)));
    }
    rotY(fmaf(xl(21), w[21], theta[21]));                    // Y(p0_7)
    float x22 = xl(22);                                      // save before restage
    __syncthreads();                                         // WAR barrier

    // ---- half B: j = 24..47 (LDS rows j-24) ----
    stage(1);
    __syncthreads();

    // Z(-(p1_7 + p2_8)): x[22] from reg, x[26] from half B
    rotZ(fmaf(x22, w[22], fmaf(xl(26 - 24), w[26], theta[22] + theta[26])));
    #pragma unroll
    for (int k = 8; k < 15; ++k) {
        const int j = 3 * k;
        rotY(fmaf(xl(j - 24), w[j], theta[j]));              // Y(p0_k)
        float ts = theta[j + 1] + theta[j + 5];
        rotZ(fmaf(xl(j - 23), w[j + 1], fmaf(xl(j - 19), w[j + 5], ts)));
    }
    rotY(fmaf(xl(45 - 24), w[45], theta[45]));               // Y(p0_15)
    rotZ(fmaf(xl(46 - 24), w[46], theta[46]));               // Z(-p1_15)

    // --- Reassemble REAL parts only ---
    if (active) {
        if (4 * b + 4 <= out_floats) {
            reinterpret_cast<float4*>(out)[b] =
                make_float4(a0r + v3r, v1r + v2i, v1r - v2i, a0r - v3r);
        } else {
            float vals[4] = {a0r + v3r, v1r + v2i, v1r - v2i, a0r - v3r};
            for (int j = 0; j < 4; ++j) {
                long long o = 4 * b + j;
                if (o < out_floats) out[o] = vals[j];
            }
        }
    }
}

extern "C" void kernel_launch(void* const* d_in, const int* in_sizes, int n_in,
                              void* d_out, int out_size, void* d_ws, size_t ws_size,
                              hipStream_t stream) {
    const float* rho_real = (const float*)d_in[0];
    const float* rho_imag = (const float*)d_in[1];
    const float* x        = (const float*)d_in[2];
    const float* w        = (const float*)d_in[3];
    const float* theta    = (const float*)d_in[4];
    float* out = (float*)d_out;

    long long nB = (long long)in_sizes[0] / 4;
    long long nX = (long long)in_sizes[2] / DD;
    long long n  = nB < nX ? nB : nX;
    if (n <= 0) return;

    int grid = (int)((n + BLK - 1) / BLK);
    qlayer_kernel<<<dim3(grid), dim3(BLK), 0, stream>>>(
        rho_real, rho_imag, x, w, theta, out, n, (long long)out_size);
}